// Round 9
// baseline (512.183 us; speedup 1.0000x reference)
//
#include <hip/hip_runtime.h>
#include <math.h>

#define BATCH 8
#define CH    64
#define NPTS  2048
#define KNN   20
#define OUTC  64

// Branchless sorted insert (ascending d[0..19], d[0] = 20th best).
// Precondition: iv > d[0].
__device__ __forceinline__ void ladder20(float (&d)[KNN], int (&id)[KNN], float iv, int ii) {
    bool ci = true;
    #pragma unroll
    for (int s = 0; s < KNN; ++s) {
        const bool  cn = (s < KNN-1) ? (iv > d[s+1]) : false;
        const float dn = (s < KNN-1) ? d[s+1] : 0.f;
        const int   gn = (s < KNN-1) ? id[s+1] : 0;
        d[s]  = cn ? dn : (ci ? iv : d[s]);
        id[s] = cn ? gn : (ci ? ii : id[s]);
        ci = cn;
    }
}

// Static 32-way mux by index bits (rule #20: no dynamic reg indexing).
__device__ __forceinline__ float mux32(const float (&r)[32], int e) {
    float s16[16], s8[8], s4[4], s2[2];
    #pragma unroll
    for (int i = 0; i < 16; ++i) s16[i] = (e & 1)  ? r[2*i+1]  : r[2*i];
    #pragma unroll
    for (int i = 0; i < 8; ++i)  s8[i]  = (e & 2)  ? s16[2*i+1]: s16[2*i];
    #pragma unroll
    for (int i = 0; i < 4; ++i)  s4[i]  = (e & 4)  ? s8[2*i+1] : s8[2*i];
    #pragma unroll
    for (int i = 0; i < 2; ++i)  s2[i]  = (e & 8)  ? s4[2*i+1] : s4[2*i];
    return (e & 16) ? s2[1] : s2[0];
}

// prep (unchanged, known-good): 512 blocks, 32-m tiles.
__global__ __launch_bounds__(256) void edgeconv_prep(
    const float* __restrict__ x, const float* __restrict__ W,
    const float* __restrict__ bias,
    float* __restrict__ y1t, float* __restrict__ zt, float* __restrict__ xx)
{
    __shared__ __align__(16) float Wt1[64*65];
    __shared__ __align__(16) float Wtd[64*65];
    __shared__ __align__(16) float xs [64*32];
    const int tx  = threadIdx.x;
    const int bid = blockIdx.x;
    const int b   = bid >> 6;
    const int m0  = (bid & 63) << 5;
    const float* xb = x + (size_t)b * (CH * NPTS);

    {
        const int o  = tx >> 2;
        const int cb = (tx & 3) << 4;
        #pragma unroll
        for (int cc = 0; cc < 16; cc += 4) {
            const float4 w1 = *(const float4*)&W[o*128 + cb + cc];
            const float4 w2 = *(const float4*)&W[o*128 + 64 + cb + cc];
            const float a1[4] = {w1.x, w1.y, w1.z, w1.w};
            const float a2[4] = {w2.x, w2.y, w2.z, w2.w};
            #pragma unroll
            for (int e = 0; e < 4; ++e) {
                Wt1[(cb+cc+e)*65 + o] = a1[e];
                Wtd[(cb+cc+e)*65 + o] = a2[e] - a1[e];
            }
        }
    }
    {
        const int c0 = tx >> 2;
        const int j0 = (tx & 3) << 3;
        *(float4*)&xs[c0*32 + j0]     = *(const float4*)&xb[(size_t)c0*NPTS + m0 + j0];
        *(float4*)&xs[c0*32 + j0 + 4] = *(const float4*)&xb[(size_t)c0*NPTS + m0 + j0 + 4];
    }
    __syncthreads();

    if (tx < 32) {
        float s = 0.f;
        #pragma unroll
        for (int c = 0; c < 64; ++c) { const float v = xs[c*32 + tx]; s = fmaf(v, v, s); }
        xx[b*NPTS + m0 + tx] = s;
    }

    const int o  = tx & 63;
    const int mg = tx >> 6;
    float y[8], z[8];
    const float bo = bias[o];
    #pragma unroll
    for (int i = 0; i < 8; ++i) { y[i] = 0.f; z[i] = bo; }
    #pragma unroll 8
    for (int c = 0; c < 64; ++c) {
        const float w1 = Wt1[c*65 + o];
        const float wd = Wtd[c*65 + o];
        float a[8];
        *(float4*)&a[0] = *(const float4*)&xs[c*32 + mg*8];
        *(float4*)&a[4] = *(const float4*)&xs[c*32 + mg*8 + 4];
        #pragma unroll
        for (int i = 0; i < 8; ++i) {
            y[i] = fmaf(w1, a[i], y[i]);
            z[i] = fmaf(wd, a[i], z[i]);
        }
    }
    #pragma unroll
    for (int i = 0; i < 8; ++i) {
        const int m = m0 + mg*8 + i;
        y1t[((size_t)b*NPTS + m)*64 + o] = y[i];
        zt [((size_t)b*NPTS + m)*64 + o] = z[i];
    }
}

// Gram+topk: grid 512 = (batch, 64-row tile, m-half of 1024 cols).
// Thread (tr=tx>>4, tc=tx&15) computes a 4-row x 8-col patch per k:
// 1 a-b128 + 2 b-b128 -> 32 FMA (LDS ratio 1.125 cyc/FMA).
// bT swizzle (FIXED from R8's overlapping layout): stride 140,
// chunk tcc at float offset tcc*8 + ((tcc>>2)<<2) -> 16 disjoint 8-float
// chunks, bank-quads covered exactly 2x (2-way aliasing = free, m136).
// After each 128-col pass, rotated-publish shuffle redistributes scores so
// thread owns row tr*4+(tc&3), col-quarter tc>>2; register top-20 per owner.
// Block ends: 4-owner tournament -> one 20-list per row per block -> scratch.
__global__ __launch_bounds__(256) void edgeconv_gram_topk(
    const float* __restrict__ x, const float* __restrict__ xx,
    float* __restrict__ lv, int* __restrict__ li)
{
    __shared__ __align__(16) float aT[64*68];    // [k][row]  17408 B
    __shared__ __align__(16) float bT[64*140];   // [k][swizzled col] 35840 B

    const int tx  = threadIdx.x;
    const int bid = blockIdx.x;
    const int b   = bid >> 6;
    const int rem = bid & 63;
    const int n0  = (rem >> 1) << 6;          // 64-row tile
    const int ms  = rem & 1;                  // m-half
    const int m0b = ms << 10;                 // 1024-col range base
    const float* xb  = x  + (size_t)b * (CH * NPTS);
    const float* xxb = xx + (size_t)b * NPTS;

    const int tr = tx >> 4;                   // 0..15 (4 rows each)
    const int tc = tx & 15;                   // 0..15 (8 cols each)
    const int lane = tx & 63;
    const int swz = (tc >> 2) << 2;           // b-tile bank stagger (non-overlap)
    const int myrow = tr*4 + (tc & 3);        // owner row after exchange

    {   // stage aT [k][row] once: thread k=tx>>2 writes rows (tx&3)*16..+15
        const int k  = tx >> 2;
        const int j0 = (tx & 3) << 4;
        #pragma unroll
        for (int i = 0; i < 16; i += 4) {
            const float4 u = *(const float4*)&xb[(size_t)k*NPTS + n0 + j0 + i];
            *(float4*)&aT[k*68 + j0 + i] = u;
        }
    }
    {   // stage bT pass 0: thread k=tx>>2, col-group cg=tx&3 (32 cols)
        const int k  = tx >> 2;
        const int cg = tx & 3;
        #pragma unroll
        for (int j = 0; j < 4; ++j) {
            const int tcc = cg*4 + j;
            const int off = k*140 + tcc*8 + ((tcc >> 2) << 2);
            *(float4*)&bT[off]     = *(const float4*)&xb[(size_t)k*NPTS + m0b + cg*32 + j*8];
            *(float4*)&bT[off + 4] = *(const float4*)&xb[(size_t)k*NPTS + m0b + cg*32 + j*8 + 4];
        }
    }

    float d[KNN]; int id[KNN];
    #pragma unroll
    for (int k = 0; k < KNN; ++k) { d[k] = -INFINITY; id[k] = 0; }
    float thr = -INFINITY;

    float xq[8];   // ||x_m||^2 for my 8 cols of current pass
    *(float4*)&xq[0] = *(const float4*)&xxb[m0b + tc*8];
    *(float4*)&xq[4] = *(const float4*)&xxb[m0b + tc*8 + 4];

    __syncthreads();    // aT + bT(p0) visible

    for (int p = 0; p < 8; ++p) {
        const int m0 = m0b + p*128;

        // prefetch next pass to registers (T14: issue early, write after barrier)
        float4 pf[8]; float4 xqn0 = {0,0,0,0}, xqn1 = {0,0,0,0};
        const int kst = tx >> 2;
        const int cg  = tx & 3;
        if (p < 7) {
            const int mn = m0 + 128;
            #pragma unroll
            for (int j = 0; j < 4; ++j) {
                pf[2*j]   = *(const float4*)&xb[(size_t)kst*NPTS + mn + cg*32 + j*8];
                pf[2*j+1] = *(const float4*)&xb[(size_t)kst*NPTS + mn + cg*32 + j*8 + 4];
            }
            xqn0 = *(const float4*)&xxb[mn + tc*8];
            xqn1 = *(const float4*)&xxb[mn + tc*8 + 4];
        }

        // ---- Gram: acc[ri][e] = dot(x_n[tr*4+ri], x_m[tc*8+e]) ----
        float acc[4][8];
        #pragma unroll
        for (int ri = 0; ri < 4; ++ri)
            #pragma unroll
            for (int e = 0; e < 8; ++e) acc[ri][e] = 0.f;

        #pragma unroll 8
        for (int k = 0; k < 64; ++k) {
            float av[4], bv[8];
            *(float4*)&av[0] = *(const float4*)&aT[k*68 + tr*4];
            *(float4*)&bv[0] = *(const float4*)&bT[k*140 + tc*8 + swz];
            *(float4*)&bv[4] = *(const float4*)&bT[k*140 + tc*8 + swz + 4];
            #pragma unroll
            for (int ri = 0; ri < 4; ++ri)
                #pragma unroll
                for (int e = 0; e < 8; ++e)
                    acc[ri][e] = fmaf(av[ri], bv[e], acc[ri][e]);
        }

        // keys: v[ri][e] = 2*dot - ||m||^2
        float v0[8], v1[8], v2[8], v3[8];
        #pragma unroll
        for (int e = 0; e < 8; ++e) {
            v0[e] = fmaf(2.f, acc[0][e], -xq[e]);
            v1[e] = fmaf(2.f, acc[1][e], -xq[e]);
            v2[e] = fmaf(2.f, acc[2][e], -xq[e]);
            v3[e] = fmaf(2.f, acc[3][e], -xq[e]);
        }

        // ---- rotated-publish exchange: 4 rounds x 8 shfl ----
        unsigned msk = 0u;
        float r[32];
        #pragma unroll
        for (int j = 0; j < 4; ++j) {
            const int rj = (tc + j) & 3;                 // which of my rows I publish
            const int srcLane = (lane & 48) | (tc & 12) | ((tc - j) & 3);
            float pub[8];
            #pragma unroll
            for (int ci = 0; ci < 8; ++ci)
                pub[ci] = (rj & 2) ? ((rj & 1) ? v3[ci] : v2[ci])
                                   : ((rj & 1) ? v1[ci] : v0[ci]);
            #pragma unroll
            for (int ci = 0; ci < 8; ++ci) {
                const float rv = __shfl(pub[ci], srcLane);
                r[j*8 + ci] = rv;
                msk |= (rv > thr) ? (1u << (j*8 + ci)) : 0u;
            }
        }

        // ---- drain: wave pays max-lane candidate count ----
        while (__any(msk != 0u)) {
            const bool act = (msk != 0u);
            const int  e   = __ffs(msk) - 1;
            msk &= msk - 1u;
            const float vv = mux32(r, e);
            if (act && vv > d[0]) {
                const int j2  = e >> 3;
                const int col = m0 + ((tc & 12) << 3) + (((tc - j2) & 3) << 3) + (e & 7);
                ladder20(d, id, vv, col);
            }
        }

        // row-shared threshold over the row's 4 owners (lanes ^4, ^8)
        float tm = d[0];
        tm = fmaxf(tm, __shfl_xor(tm, 4));
        tm = fmaxf(tm, __shfl_xor(tm, 8));
        thr = tm;

        __syncthreads();      // all bT reads of pass p done
        if (p < 7) {          // commit next b-tile + keys
            #pragma unroll
            for (int j = 0; j < 4; ++j) {
                const int tcc = cg*4 + j;
                const int off = kst*140 + tcc*8 + ((tcc >> 2) << 2);
                *(float4*)&bT[off]     = pf[2*j];
                *(float4*)&bT[off + 4] = pf[2*j+1];
            }
            *(float4*)&xq[0] = xqn0;
            *(float4*)&xq[4] = xqn1;
        }
        __syncthreads();      // bT(p+1) visible
    }

    // ---- 4-owner tournament per row (lanes ^4, ^8); lane tc<4 writes ----
    const int g = b*NPTS + n0 + myrow;        // global row id
    for (int k = 0; k < KNN; ++k) {
        float bv = d[KNN-1]; int bg = id[KNN-1];
        {
            const float ov = __shfl_xor(bv, 4); const int og = __shfl_xor(bg, 4);
            if (ov > bv || (ov == bv && og < bg)) { bv = ov; bg = og; }
        }
        {
            const float ov = __shfl_xor(bv, 8); const int og = __shfl_xor(bg, 8);
            if (ov > bv || (ov == bv && og < bg)) { bv = ov; bg = og; }
        }
        if ((tc & 12) == 0) { lv[(size_t)g*40 + ms*20 + k] = bv; li[(size_t)g*40 + ms*20 + k] = bg; }
        if (d[KNN-1] == bv && id[KNN-1] == bg) {   // unique winner pops
            #pragma unroll
            for (int s = KNN-1; s > 0; --s) { d[s] = d[s-1]; id[s] = id[s-1]; }
            d[0] = -INFINITY; id[0] = 0;
        }
    }
}

// merge + epilogue: 512 blocks x 32 rows. 2-head merge of the two m-half
// lists (LDS-staged), then gather/lrelu/max.
__global__ __launch_bounds__(256) void edgeconv_merge(
    const float* __restrict__ lv, const int* __restrict__ li,
    const float* __restrict__ y1t, const float* __restrict__ zt,
    float* __restrict__ out)
{
    __shared__ __align__(16) float Lv[32*40];
    __shared__ __align__(16) int   Li[32*40];
    __shared__ __align__(16) int   ml[32*20];
    __shared__ __align__(16) float outbuf[32*68];

    const int tx  = threadIdx.x;
    const int blk = blockIdx.x;

    // coalesced stage of this block's 32x40 list entries
    for (int i = tx; i < 1280; i += 256) {
        Lv[i] = lv[(size_t)blk*1280 + i];
        Li[i] = li[(size_t)blk*1280 + i];
    }
    __syncthreads();

    if (tx < 32) {   // serial 2-head merge per row; comparator == lax.top_k
        const int base = tx*40;
        int i0 = 0, i1 = 20;
        for (int k = 0; k < KNN; ++k) {
            const float va = Lv[base + i0]; const int ia = Li[base + i0];
            const float vb = Lv[base + i1]; const int ib = Li[base + i1];
            const bool takeA = (va > vb) || (va == vb && ia < ib);
            ml[tx*20 + k] = takeA ? ia : ib;
            i0 += takeA ? 1 : 0;
            i1 += takeA ? 0 : 1;
        }
    }
    __syncthreads();

    // epilogue: out[b,o,n] = max_k lrelu(y1t[m_k][o] + zt[n][o])
    const int lane = tx & 63;
    const int w    = tx >> 6;
    const int b    = blk >> 6;
    const int n0b  = (blk & 63) << 5;
    const float* y1b = y1t + (size_t)b * NPTS * 64;
    const float* ztb = zt  + (size_t)b * NPTS * 64;

    #pragma unroll
    for (int rr = 0; rr < 8; ++rr) {
        const int rw = w*8 + rr;
        const int n  = n0b + rw;
        const float zv = ztb[(size_t)n*64 + lane];
        float acc = -INFINITY;
        #pragma unroll
        for (int k = 0; k < KNN; ++k) {
            const int m = ml[rw*20 + k];
            const float vv = y1b[(size_t)m*64 + lane];
            float h = vv + zv;
            h = fmaxf(h, 0.2f*h);
            acc = fmaxf(acc, h);
        }
        outbuf[rw*68 + lane] = acc;
    }
    __syncthreads();
    float* ob = out + (size_t)b * OUTC * NPTS;
    #pragma unroll
    for (int i = 0; i < 8; ++i) {
        const int o  = w*16 + i*2 + (lane >> 5);
        const int nn = lane & 31;
        ob[(size_t)o*NPTS + n0b + nn] = outbuf[nn*68 + o];
    }
}

extern "C" void kernel_launch(void* const* d_in, const int* in_sizes, int n_in,
                              void* d_out, int out_size, void* d_ws, size_t ws_size,
                              hipStream_t stream) {
    const float* x    = (const float*)d_in[0];   // (8,64,2048)
    const float* W    = (const float*)d_in[1];   // (64,128)
    const float* bias = (const float*)d_in[2];   // (64,)
    float* out = (float*)d_out;                  // (8,64,2048)

    // ws: y1t 4MB | zt 4MB | xx 64KB | lv 2.62MB | li 2.62MB  (~13.7MB)
    float* y1t = (float*)d_ws;
    float* zt  = y1t + (size_t)BATCH * NPTS * 64;
    float* xx  = zt  + (size_t)BATCH * NPTS * 64;
    float* lv  = xx  + (size_t)BATCH * NPTS;
    int*   li  = (int*)(lv + (size_t)BATCH * NPTS * 40);

    edgeconv_prep<<<BATCH * (NPTS/32), 256, 0, stream>>>(x, W, bias, y1t, zt, xx);
    edgeconv_gram_topk<<<BATCH * (NPTS/64) * 2, 256, 0, stream>>>(x, xx, lv, li);
    edgeconv_merge<<<(BATCH * NPTS) / 32, 256, 0, stream>>>(lv, li, y1t, zt, out);
}